// Round 3
// baseline (1310.890 us; speedup 1.0000x reference)
//
#include <hip/hip_runtime.h>

typedef __bf16 bf16x8 __attribute__((ext_vector_type(8)));
typedef float  f32x4  __attribute__((ext_vector_type(4)));

#define TW     16      // tile width (pixels)
#define TH     4       // tile height
#define NPX    64      // pixels per block
#define HLW    22      // halo width  = TW+6
#define HLH    10      // halo height = TH+6
#define HN     220     // HLW*HLH
#define KK     7
#define NCLASS 49
#define IMW    256
#define IMH    256
#define HW     65536   // 256*256

__global__ __launch_bounds__(256, 4)
void gtnet_kernel(const float* __restrict__ im_input,
                  const float* __restrict__ gt_motion,
                  const float* __restrict__ m_kernel,
                  float* __restrict__ out_pred,
                  float* __restrict__ out_mask)
{
    // omW: first om accumulator om[n*64+px] (bank = px%32, conflict-free scatter),
    // then reused as W[px*49+t]. 3136 floats either way.
    __shared__ float  omW[NCLASS * NPX];                 // 12544 B
    __shared__ float  Klds[NCLASS * NCLASS];             // 9604 B (f32 for scatter)
    __shared__ __align__(16) __bf16 KT[64 * 64];         // 8192 B (B-operand K^T, padded)
    __shared__ float2 halo[HN];                          // 1760 B (ay,ax; sentinel -8)
    __shared__ float  iml[3 * HN];                       // 2640 B (im halo)
    __shared__ float  pr_red[4 * 3 * NPX];               // 3072 B (cross-wave pred partials)
    // total 37812 B -> 4 blocks/CU, 16 waves/CU

    const int tid  = threadIdx.x;
    const int wv   = tid >> 6, lane = tid & 63;
    const int lx   = lane & 15, ly = lane >> 4;          // pixel coords within tile
    const int x0 = blockIdx.x * TW, y0 = blockIdx.y * TH;
    const int b  = blockIdx.z;

    // ---------------- phase 1: staging ----------------
    for (int i = tid; i < NCLASS * NCLASS; i += 256) Klds[i] = m_kernel[i];

    for (int i = tid; i < 64 * 64; i += 256) {
        int t = i >> 6, k = i & 63;
        KT[i] = (__bf16)((t < NCLASS && k < NCLASS) ? m_kernel[k * NCLASS + t] : 0.0f);
    }

    const float* mot_x = gt_motion + (size_t)b * 2 * HW;  // channel 0 -> ax
    const float* mot_y = mot_x + HW;                      // channel 1 -> ay
    for (int i = tid; i < HN; i += 256) {
        int hy = i / HLW, hx = i - hy * HLW;
        int gy = y0 - 3 + hy, gx = x0 - 3 + hx;
        float2 v;
        if (gy >= 0 && gy < IMH && gx >= 0 && gx < IMW) {
            int off = gy * IMW + gx;
            v.x = mot_y[off] + 3.0f;
            v.y = mot_x[off] + 3.0f;
        } else {
            v.x = -8.0f; v.y = -8.0f;
        }
        halo[i] = v;
    }

    const float* imP = im_input + ((size_t)b * 6 + 3) * HW;  // last 3 channels
    for (int i = tid; i < 3 * HN; i += 256) {
        int c  = i / HN, r = i - c * HN;
        int hy = r / HLW, hx = r - hy * HLW;
        int gy = y0 - 3 + hy, gx = x0 - 3 + hx;
        float v = 0.0f;
        if (gy >= 0 && gy < IMH && gx >= 0 && gx < IMW)
            v = imP[c * HW + gy * IMW + gx];
        iml[i] = v;
    }

    for (int i = tid; i < NCLASS * NPX; i += 256) omW[i] = 0.0f;

    __syncthreads();

    // ---------------- phase 2: m_mask write (classes split across waves) ----------------
    {
        float2 h = halo[(ly + 3) * HLW + (lx + 3)];
        float iyf = floorf(h.x), ixf = floorf(h.y);
        float fy = h.x - iyf,    fx = h.y - ixf;
        int   iy = (int)iyf,     ix = (int)ixf;
        float wyA[KK], wxB[KK];
        #pragma unroll
        for (int a = 0; a < KK; a++) {
            wyA[a] = (a == iy) ? (1.0f - fy) : ((a == iy + 1) ? fy : 0.0f);
            wxB[a] = (a == ix) ? (1.0f - fx) : ((a == ix + 1) ? fx : 0.0f);
        }
        float* mm = out_mask + (size_t)b * NCLASS * HW + (y0 + ly) * IMW + (x0 + lx);
        #pragma unroll
        for (int c = 0; c < NCLASS; c++) {
            if ((c & 3) == wv)   // wave-uniform branch, c compile-time
                mm[(size_t)c * HW] = wyA[c / KK] * wxB[c % KK];
        }
    }

    // ---------------- phase 3: om scatter (neighbors split across waves) ----------------
    #pragma unroll
    for (int s = 0; s < NCLASS; s++) {
        if ((s & 3) != wv) continue;       // wave-uniform
        const int u = s / KK, v2 = s % KK;
        float2 h = halo[(ly + u) * HLW + (lx + v2)];
        float ayc = h.x, axc = h.y;
        float iyf = floorf(ayc), ixf = floorf(axc);
        float fy = ayc - iyf,    fx = axc - ixf;
        bool  valid = (ayc >= 0.0f);
        float wy0 = valid ? (1.0f - fy) : 0.0f;
        float wy1 = valid ? fy : 0.0f;
        int   n00 = valid ? ((int)iyf * KK + (int)ixf) : 0;
        const float* kb = &Klds[n00 * NCLASS + s];
        float k00 = kb[0];
        float k01 = kb[NCLASS];
        float k10 = kb[KK * NCLASS];
        float k11 = kb[(KK + 1) * NCLASS];
        float wx0 = 1.0f - fx;
        float* ob = &omW[n00 * NPX + lane];
        atomicAdd(ob,             wy0 * wx0 * k00);
        atomicAdd(ob + NPX,       wy0 * fx  * k01);
        atomicAdd(ob + 7 * NPX,   wy1 * wx0 * k10);
        atomicAdd(ob + 8 * NPX,   wy1 * fx  * k11);
    }

    __syncthreads();   // om complete

    // ---------------- phase 4: MFMA fragments (wave wv owns px slab wv*16..wv*16+15) ----
    const int mpx  = wv * 16 + (lane & 15);
    const int krow = (lane >> 4) * 8;
    bf16x8 af[2];
    #pragma unroll
    for (int kit = 0; kit < 2; kit++) {
        int k0 = kit * 32 + krow;
        bf16x8 a;
        #pragma unroll
        for (int j = 0; j < 8; j++) {
            int n  = k0 + j;
            int nn = (n < NCLASS) ? n : (NCLASS - 1);
            float v = omW[nn * NPX + mpx];
            a[j] = (__bf16)((n < NCLASS) ? v : 0.0f);
        }
        af[kit] = a;
    }
    bf16x8 bfr[2][4];
    #pragma unroll
    for (int kit = 0; kit < 2; kit++) {
        #pragma unroll
        for (int nt = 0; nt < 4; nt++) {
            int t  = nt * 16 + (lane & 15);
            int k0 = kit * 32 + krow;
            bfr[kit][nt] = *reinterpret_cast<const bf16x8*>(&KT[t * 64 + k0]);
        }
    }

    __syncthreads();   // all om reads done before W overwrites the buffer

    // ---------------- phase 5: W[64x49] = om[64x64] x K^T[64x49pad] ----------------
    f32x4 acc[4];
    #pragma unroll
    for (int nt = 0; nt < 4; nt++) {
        f32x4 c = {0.0f, 0.0f, 0.0f, 0.0f};
        c = __builtin_amdgcn_mfma_f32_16x16x32_bf16(af[0], bfr[0][nt], c, 0, 0, 0);
        c = __builtin_amdgcn_mfma_f32_16x16x32_bf16(af[1], bfr[1][nt], c, 0, 0, 0);
        acc[nt] = c;
    }
    // C/D layout: col = lane&15 (t), row = (lane>>4)*4 + r (px within slab)
    #pragma unroll
    for (int nt = 0; nt < 4; nt++) {
        int t = nt * 16 + (lane & 15);
        if (t < NCLASS) {
            #pragma unroll
            for (int r = 0; r < 4; r++) {
                int px = wv * 16 + (lane >> 4) * 4 + r;
                omW[px * NCLASS + t] = acc[nt][r];
            }
        }
    }

    __syncthreads();   // W ready

    // ---------------- phase 6: apply effective 7x7 (taps split across waves) ----------
    float a0 = 0.0f, a1 = 0.0f, a2 = 0.0f;
    #pragma unroll
    for (int t = 0; t < NCLASS; t++) {
        if ((t & 3) != wv) continue;       // wave-uniform
        const int p = t / KK, q = t % KK;
        float wvv = omW[lane * NCLASS + t];
        int   hi = (ly + p) * HLW + (lx + q);
        a0 = fmaf(wvv, iml[hi],           a0);
        a1 = fmaf(wvv, iml[hi + HN],      a1);
        a2 = fmaf(wvv, iml[hi + 2 * HN],  a2);
    }
    pr_red[wv * 192 + 0 * NPX + lane] = a0;
    pr_red[wv * 192 + 1 * NPX + lane] = a1;
    pr_red[wv * 192 + 2 * NPX + lane] = a2;

    __syncthreads();

    if (tid < 3 * NPX) {
        float v = pr_red[tid] + pr_red[192 + tid] + pr_red[384 + tid] + pr_red[576 + tid];
        int c = tid >> 6, px = tid & 63;
        out_pred[(size_t)b * 3 * HW + (size_t)c * HW +
                 (y0 + (px >> 4)) * IMW + (x0 + (px & 15))] = v;
    }
}

extern "C" void kernel_launch(void* const* d_in, const int* in_sizes, int n_in,
                              void* d_out, int out_size, void* d_ws, size_t ws_size,
                              hipStream_t stream) {
    const float* im_input  = (const float*)d_in[0];
    // d_in[1] = im_output: unused by the reference computation
    const float* gt_motion = (const float*)d_in[2];
    const float* m_kernel  = (const float*)d_in[3];

    float* pred = (float*)d_out;                        // (16,3,256,256)
    float* mask = pred + (size_t)16 * 3 * HW;           // (16,49,256,256)

    dim3 grid(IMW / TW, IMH / TH, 16);
    dim3 block(256);
    hipLaunchKernelGGL(gtnet_kernel, grid, block, 0, stream,
                       im_input, gt_motion, m_kernel, pred, mask);
}